// Round 1
// baseline (1163.292 us; speedup 1.0000x reference)
//
#include <hip/hip_runtime.h>
#include <hip/hip_bf16.h>

#define EPSF 1e-5f
#define IOU_THRF 0.9f
#define NBOX 9216
#define NWORDS 144   // 9216/64

// ---------------- depthwise 3x3 conv, C=256, 32x32, pad 1 ----------------
__global__ __launch_bounds__(256) void dw_conv(const float* __restrict__ x,
                                               const float* __restrict__ w,
                                               float* __restrict__ h0) {
    int idx = blockIdx.x * 256 + threadIdx.x;   // 262144 threads
    int c = idx >> 10, p = idx & 1023;
    int yy = p >> 5, xx = p & 31;
    const float* xi = x + (c << 10);
    const float* wc = w + c * 9;
    float acc = 0.f;
    #pragma unroll
    for (int dy = -1; dy <= 1; ++dy) {
        int y2 = yy + dy;
        if ((unsigned)y2 >= 32u) continue;
        #pragma unroll
        for (int dx = -1; dx <= 1; ++dx) {
            int x2 = xx + dx;
            if ((unsigned)x2 >= 32u) continue;
            acc += wc[(dy + 1) * 3 + (dx + 1)] * xi[y2 * 32 + x2];
        }
    }
    h0[idx] = acc;
}

// ---------------- pointwise 256x256 GEMM + BN1 + leaky relu ----------------
// grid (4 p-tiles, 64 o-groups of 4), 256 thr
__global__ __launch_bounds__(256) void pw_conv(const float* __restrict__ h0,
                                               const float* __restrict__ w,
                                               const float* __restrict__ g,
                                               const float* __restrict__ b,
                                               const float* __restrict__ mu,
                                               const float* __restrict__ var,
                                               float* __restrict__ h1) {
    int p = blockIdx.x * 256 + threadIdx.x;
    int o0 = blockIdx.y * 4;
    float acc0 = 0.f, acc1 = 0.f, acc2 = 0.f, acc3 = 0.f;
    for (int c = 0; c < 256; ++c) {
        float hv = h0[(c << 10) + p];
        acc0 += w[(o0 + 0) * 256 + c] * hv;
        acc1 += w[(o0 + 1) * 256 + c] * hv;
        acc2 += w[(o0 + 2) * 256 + c] * hv;
        acc3 += w[(o0 + 3) * 256 + c] * hv;
    }
    float accs[4] = {acc0, acc1, acc2, acc3};
    #pragma unroll
    for (int k = 0; k < 4; ++k) {
        int o = o0 + k;
        float inv = 1.0f / sqrtf(var[o] + EPSF);
        float v = (accs[k] - mu[o]) * (inv * g[o]) + b[o];
        v = (v >= 0.f) ? v : 0.01f * v;
        h1[(o << 10) + p] = v;
    }
}

// ---------------- heads: anc (36 ch) + obj (9 ch) GEMV + BN + decode ----------------
// grid (4 p-tiles, 45 channels), 256 thr
__global__ __launch_bounds__(256) void heads(const float* __restrict__ h1,
                                             const float* __restrict__ anc_w,
                                             const float* __restrict__ ag,
                                             const float* __restrict__ ab,
                                             const float* __restrict__ am,
                                             const float* __restrict__ av,
                                             const float* __restrict__ obj_w,
                                             const float* __restrict__ og,
                                             const float* __restrict__ ob,
                                             const float* __restrict__ om,
                                             const float* __restrict__ ov,
                                             const float* __restrict__ anchors,
                                             float* __restrict__ boxes,
                                             float* __restrict__ scores) {
    int p = blockIdx.x * 256 + threadIdx.x;
    int o = blockIdx.y;
    const float* wrow = (o < 36) ? (anc_w + o * 256) : (obj_w + (o - 36) * 256);
    float acc = 0.f;
    for (int c = 0; c < 256; ++c) acc += wrow[c] * h1[(c << 10) + p];
    if (o < 36) {
        float inv = 1.0f / sqrtf(av[o] + EPSF);
        float v = (acc - am[o]) * (inv * ag[o]) + ab[o];
        v = fminf(fmaxf(v, 0.f), 6.f);           // clip 0..6
        int a = o >> 2, k = o & 3;
        float anch = anchors[a * 4 + k];
        float val = (k < 2) ? (v + anch) : (expf(v) * anch);
        boxes[(size_t)(a * 1024 + p) * 4 + k] = val;
    } else {
        int a = o - 36;
        float inv = 1.0f / sqrtf(ov[a] + EPSF);
        float v = (acc - om[a]) * (inv * og[a]) + ob[a];
        scores[a * 1024 + p] = 1.0f / (1.0f + expf(-v));
    }
}

// ---------------- rank = stable-descending-argsort position, O(N^2) count ----------------
// grid (36 n-blocks, 8 m-chunks of 1152), 256 thr
__global__ __launch_bounds__(256) void rank_partial(const float* __restrict__ scores,
                                                    unsigned* __restrict__ rank) {
    __shared__ float4 sm[288];
    int mbase = blockIdx.y * 1152;
    for (int t = threadIdx.x; t < 288; t += 256)
        sm[t] = ((const float4*)(scores + mbase))[t];
    __syncthreads();
    int n = blockIdx.x * 256 + threadIdx.x;
    float s = scores[n];
    unsigned cnt = 0;
    for (int q = 0; q < 288; ++q) {
        float4 v = sm[q];
        int m = mbase + q * 4;
        cnt += (v.x > s) || (v.x == s && (m + 0) < n);
        cnt += (v.y > s) || (v.y == s && (m + 1) < n);
        cnt += (v.z > s) || (v.z == s && (m + 2) < n);
        cnt += (v.w > s) || (v.w == s && (m + 3) < n);
    }
    atomicAdd(&rank[n], cnt);
}

// ---------------- scatter into sorted order ----------------
__global__ __launch_bounds__(256) void scatter_sorted(const float* __restrict__ boxes,
                                                      const unsigned* __restrict__ rank,
                                                      int* __restrict__ order,
                                                      float* __restrict__ sboxes,
                                                      float* __restrict__ sareas) {
    int n = blockIdx.x * 256 + threadIdx.x;
    unsigned r = rank[n];
    order[r] = n;
    float4 bx = ((const float4*)boxes)[n];
    ((float4*)sboxes)[r] = bx;
    sareas[r] = (bx.z - bx.x) * (bx.w - bx.y);
}

// ---------------- suppression bitmask, [word][row] layout ----------------
// grid (144 words, 36 row-blocks), 256 thr
__global__ __launch_bounds__(256) void build_mask(const float* __restrict__ sboxes,
                                                  const float* __restrict__ sareas,
                                                  unsigned long long* __restrict__ mask,
                                                  unsigned* __restrict__ rownz) {
    __shared__ float X1[64], Y1[64], X2[64], Y2[64], AR[64];
    int wj = blockIdx.x;
    int i = blockIdx.y * 256 + threadIdx.x;
    int j0 = wj * 64;
    if (threadIdx.x < 64) {
        int j = j0 + threadIdx.x;
        float4 b = ((const float4*)sboxes)[j];
        X1[threadIdx.x] = b.x; Y1[threadIdx.x] = b.y;
        X2[threadIdx.x] = b.z; Y2[threadIdx.x] = b.w;
        AR[threadIdx.x] = sareas[j];
    }
    __syncthreads();
    unsigned long long wbits = 0ull;
    if (j0 + 63 > i) {   // word has at least one column j > i
        float4 b = ((const float4*)sboxes)[i];
        float ar = sareas[i];
        #pragma unroll 8
        for (int t = 0; t < 64; ++t) {
            float ix = fminf(b.z, X2[t]) - fmaxf(b.x, X1[t]);
            float iy = fminf(b.w, Y2[t]) - fmaxf(b.y, Y1[t]);
            float inter = fmaxf(ix, 0.f) * fmaxf(iy, 0.f);
            float iou = inter / (ar + AR[t] - inter);
            if (iou > IOU_THRF && (j0 + t) > i) wbits |= (1ull << t);
        }
    }
    mask[(size_t)wj * NBOX + i] = wbits;
    if (wbits) atomicOr(&rownz[i], 1u);
}

// ---------------- serial greedy scan, single wave, remv in registers ----------------
__device__ inline unsigned long long shfl_u64(unsigned long long v, int src) {
    int lo = __shfl((int)(unsigned)(v & 0xffffffffull), src, 64);
    int hi = __shfl((int)(unsigned)(v >> 32), src, 64);
    return ((unsigned long long)(unsigned)hi << 32) | (unsigned)lo;
}

__global__ __launch_bounds__(64) void nms_scan(const unsigned long long* __restrict__ mask,
                                               const unsigned* __restrict__ rownz,
                                               unsigned long long* __restrict__ remv_out) {
    __shared__ unsigned char rnz[NBOX];
    int lane = threadIdx.x;
    for (int t = lane; t < NBOX; t += 64) rnz[t] = (unsigned char)(rownz[t] != 0u);
    __syncthreads();
    // lane owns words: lane (slot0), lane+64 (slot1), lane+128 (slot2, lanes<16)
    unsigned long long r0 = 0ull, r1 = 0ull, r2 = 0ull;
    for (int i = 0; i < NBOX; ++i) {
        int wi = i >> 6;
        int slot = wi >> 6;        // 0,1,2 (uniform)
        int src = wi & 63;         // owning lane (uniform)
        unsigned long long w = (slot == 0) ? r0 : ((slot == 1) ? r1 : r2);
        w = shfl_u64(w, src);
        bool alive = ((w >> (i & 63)) & 1ull) == 0ull;
        if (alive && rnz[i]) {     // wave-uniform branch
            unsigned long long m0 = mask[(size_t)lane * NBOX + i];
            unsigned long long m1 = mask[(size_t)(lane + 64) * NBOX + i];
            unsigned long long m2 = (lane < 16) ? mask[(size_t)(lane + 128) * NBOX + i] : 0ull;
            r0 |= m0; r1 |= m1; r2 |= m2;
        }
    }
    remv_out[lane] = r0;
    remv_out[lane + 64] = r1;
    if (lane < 16) remv_out[lane + 128] = r2;
}

// ---------------- finalize: out[n] = {boxes*m, score*m} ----------------
__global__ __launch_bounds__(256) void finalize(const float* __restrict__ boxes,
                                                const float* __restrict__ scores,
                                                const int* __restrict__ order,
                                                const unsigned long long* __restrict__ remv,
                                                float* __restrict__ out) {
    int i = blockIdx.x * 256 + threadIdx.x;    // sorted index
    bool alive = ((remv[i >> 6] >> (i & 63)) & 1ull) == 0ull;
    int n = order[i];
    float m = alive ? 1.f : 0.f;
    float4 b = ((const float4*)boxes)[n];
    out[(size_t)n * 5 + 0] = b.x * m;
    out[(size_t)n * 5 + 1] = b.y * m;
    out[(size_t)n * 5 + 2] = b.z * m;
    out[(size_t)n * 5 + 3] = b.w * m;
    out[(size_t)n * 5 + 4] = scores[n] * m;
}

extern "C" void kernel_launch(void* const* d_in, const int* in_sizes, int n_in,
                              void* d_out, int out_size, void* d_ws, size_t ws_size,
                              hipStream_t stream) {
    const float* x      = (const float*)d_in[0];
    const float* anchors= (const float*)d_in[1];
    const float* dw_w   = (const float*)d_in[2];
    const float* pw_w   = (const float*)d_in[3];
    const float* bn1g   = (const float*)d_in[4];
    const float* bn1b   = (const float*)d_in[5];
    const float* bn1m   = (const float*)d_in[6];
    const float* bn1v   = (const float*)d_in[7];
    const float* anc_w  = (const float*)d_in[8];
    const float* ag     = (const float*)d_in[9];
    const float* ab     = (const float*)d_in[10];
    const float* am     = (const float*)d_in[11];
    const float* av     = (const float*)d_in[12];
    const float* obj_w  = (const float*)d_in[13];
    const float* og     = (const float*)d_in[14];
    const float* ob     = (const float*)d_in[15];
    const float* om     = (const float*)d_in[16];
    const float* ov     = (const float*)d_in[17];
    float* out = (float*)d_out;

    char* ws = (char*)d_ws;
    size_t off = 0;
    auto alloc = [&](size_t bytes) -> char* {
        char* p = ws + off;
        off = (off + bytes + 255) & ~(size_t)255;
        return p;
    };
    float* h0      = (float*)alloc(256 * 1024 * 4);
    float* h1      = (float*)alloc(256 * 1024 * 4);
    float* boxes   = (float*)alloc(NBOX * 4 * 4);
    float* scores  = (float*)alloc(NBOX * 4);
    unsigned* rank = (unsigned*)alloc(NBOX * 4);
    unsigned* rownz= (unsigned*)alloc(NBOX * 4);
    int* order     = (int*)alloc(NBOX * 4);
    float* sboxes  = (float*)alloc(NBOX * 4 * 4);
    float* sareas  = (float*)alloc(NBOX * 4);
    unsigned long long* remv = (unsigned long long*)alloc(NWORDS * 8);
    unsigned long long* mask = (unsigned long long*)alloc((size_t)NBOX * NWORDS * 8);

    hipMemsetAsync(rank, 0, NBOX * 4, stream);
    hipMemsetAsync(rownz, 0, NBOX * 4, stream);

    dw_conv<<<1024, 256, 0, stream>>>(x, dw_w, h0);
    pw_conv<<<dim3(4, 64), 256, 0, stream>>>(h0, pw_w, bn1g, bn1b, bn1m, bn1v, h1);
    heads<<<dim3(4, 45), 256, 0, stream>>>(h1, anc_w, ag, ab, am, av,
                                           obj_w, og, ob, om, ov, anchors, boxes, scores);
    rank_partial<<<dim3(36, 8), 256, 0, stream>>>(scores, rank);
    scatter_sorted<<<36, 256, 0, stream>>>(boxes, rank, order, sboxes, sareas);
    build_mask<<<dim3(NWORDS, 36), 256, 0, stream>>>(sboxes, sareas, mask, rownz);
    nms_scan<<<1, 64, 0, stream>>>(mask, rownz, remv);
    finalize<<<36, 256, 0, stream>>>(boxes, scores, order, remv, out);
}